// Round 1
// baseline (333.187 us; speedup 1.0000x reference)
//
#include <hip/hip_runtime.h>

#define BB 32
#define TT 1024
#define VV 512
#define SS 128
#define LL 257   // 2*S+1

static constexpr float NEG2   = -1e30f;               // "minus inf" in log2 domain
static constexpr float INV_LN2 = 1.4426950408889634f;
static constexpr float LN2     = 0.6931471805599453f;

// ---------------- Kernel 1: per-(b,t) logsumexp over V, stored in log2 units ----
// One wave (64 lanes) per row of 512 floats; 4 rows per 256-thread block.
__global__ __launch_bounds__(256) void ctc_lse_kernel(
    const float* __restrict__ logits, float* __restrict__ lse2) {
  int row  = blockIdx.x * 4 + (threadIdx.x >> 6);
  int lane = threadIdx.x & 63;
  if (row >= BB * TT) return;

  const float4* r4 = reinterpret_cast<const float4*>(logits + (size_t)row * VV);
  float4 a = r4[lane];        // elems 4*lane .. 4*lane+3
  float4 b = r4[lane + 64];   // elems 256+4*lane ..

  float m = fmaxf(fmaxf(fmaxf(a.x, a.y), fmaxf(a.z, a.w)),
                  fmaxf(fmaxf(b.x, b.y), fmaxf(b.z, b.w)));
  #pragma unroll
  for (int off = 32; off; off >>= 1) m = fmaxf(m, __shfl_xor(m, off, 64));

  float s = exp2f((a.x - m) * INV_LN2) + exp2f((a.y - m) * INV_LN2) +
            exp2f((a.z - m) * INV_LN2) + exp2f((a.w - m) * INV_LN2) +
            exp2f((b.x - m) * INV_LN2) + exp2f((b.y - m) * INV_LN2) +
            exp2f((b.z - m) * INV_LN2) + exp2f((b.w - m) * INV_LN2);
  #pragma unroll
  for (int off = 32; off; off >>= 1) s += __shfl_xor(s, off, 64);

  if (lane == 0) lse2[row] = m * INV_LN2 + log2f(s);
}

// ---------------- Kernel 2: CTC alpha recursion, one block per batch ------------
// 320 threads (5 waves); threads 0..256 each own one extended-label state.
// alpha kept in LDS, double buffered; all values in log2 domain.
__global__ __launch_bounds__(320) void ctc_dp_kernel(
    const float* __restrict__ logits, const int* __restrict__ targets,
    const int* __restrict__ loglen, const int* __restrict__ tgtlen,
    const float* __restrict__ lse2, float* __restrict__ out) {
  const int b = blockIdx.x;
  const int s = threadIdx.x;
  const bool active = (s < LL);

  __shared__ float A[2][264];

  const int len = loglen[b];   // in [512, 1024]
  const int tl  = tgtlen[b];   // in [64, 128]

  // Per-state constants: extended label and skip-transition flag.
  int e = 0;            // blank
  bool skip = false;
  if (active && (s & 1)) {
    int j = s >> 1;
    e = targets[b * SS + j];
    skip = (s >= 3) && (e != 0) && (e != targets[b * SS + j - 1]);
  }

  const float* lrow = logits + (size_t)b * TT * VV;
  const float* lseb = lse2 + b * TT;

  // init t = 0
  if (active) {
    float lp0 = lrow[e] * INV_LN2 - lseb[0];
    float v = NEG2;
    if (s == 0) v = lp0;
    else if (s == 1 && tl > 0) v = lp0;
    A[0][s] = v;
  }
  __syncthreads();

  // prefetch t = 1
  float rawn = 0.0f, lsen = 0.0f;
  if (active && len > 1) { rawn = lrow[(size_t)VV + e]; lsen = lseb[1]; }

  for (int t = 1; t < len; ++t) {
    float lp = rawn * INV_LN2 - lsen;
    int tn = t + 1;
    if (active && tn < len) {   // prefetch next step (hides gather latency)
      rawn = lrow[(size_t)tn * VV + e];
      lsen = lseb[tn];
    }
    const int cur = t & 1, prev = cur ^ 1;
    if (active) {
      float a0 = A[prev][s];
      float a1 = (s >= 1) ? A[prev][s - 1] : NEG2;
      float a2 = skip ? A[prev][s - 2] : NEG2;
      float m  = fmaxf(fmaxf(a0, a1), a2);
      float sum = exp2f(a0 - m) + exp2f(a1 - m) + exp2f(a2 - m);
      A[cur][s] = m + log2f(sum) + lp;
    }
    __syncthreads();
  }

  if (threadIdx.x == 0) {
    const int last = (len - 1) & 1;
    const int ib = 2 * tl;
    const int il = (2 * tl - 1) > 0 ? (2 * tl - 1) : 0;
    float ab = A[last][ib];
    float al = (tl > 0) ? A[last][il] : NEG2;
    float m  = fmaxf(ab, al);
    float r  = m + log2f(exp2f(ab - m) + exp2f(al - m));
    out[b] = -r * LN2;
  }
}

extern "C" void kernel_launch(void* const* d_in, const int* in_sizes, int n_in,
                              void* d_out, int out_size, void* d_ws, size_t ws_size,
                              hipStream_t stream) {
  const float* logits  = (const float*)d_in[0];
  const int*   targets = (const int*)d_in[1];
  const int*   loglen  = (const int*)d_in[2];
  const int*   tgtlen  = (const int*)d_in[3];
  float* out = (float*)d_out;
  float* lse2 = (float*)d_ws;   // B*T floats = 128 KiB

  ctc_lse_kernel<<<(BB * TT) / 4, 256, 0, stream>>>(logits, lse2);
  ctc_dp_kernel<<<BB, 320, 0, stream>>>(logits, targets, loglen, tgtlen, lse2, out);
}